// Round 1
// baseline (475.377 us; speedup 1.0000x reference)
//
#include <hip/hip_runtime.h>
#include <math.h>

#define N_NODES 50000
#define F_IN    128
#define HID     256
#define NCLS    40

// ---------------- CSR build ----------------

__global__ void count_kernel(const int* __restrict__ dst, int* __restrict__ cnt, int E) {
    int i = blockIdx.x * blockDim.x + threadIdx.x;
    if (i < E) atomicAdd(&cnt[dst[i]], 1);
}

__global__ void block_sum_kernel(const int* __restrict__ cnt, int* __restrict__ bsum, int N) {
    __shared__ int sdata[256];
    int i = blockIdx.x * 256 + threadIdx.x;
    sdata[threadIdx.x] = (i < N) ? cnt[i] : 0;
    __syncthreads();
    for (int off = 128; off; off >>= 1) {
        if (threadIdx.x < off) sdata[threadIdx.x] += sdata[threadIdx.x + off];
        __syncthreads();
    }
    if (threadIdx.x == 0) bsum[blockIdx.x] = sdata[0];
}

__global__ void scan_bsum_kernel(int* bsum, int nb) {
    __shared__ int sdata[1024];
    int t = threadIdx.x;
    int v = (t < nb) ? bsum[t] : 0;
    sdata[t] = v;
    __syncthreads();
    for (int off = 1; off < 1024; off <<= 1) {
        int u = (t >= off) ? sdata[t - off] : 0;
        __syncthreads();
        sdata[t] += u;
        __syncthreads();
    }
    if (t < nb) bsum[t] = sdata[t] - v;   // exclusive
}

__global__ void scan_final_kernel(const int* __restrict__ cnt, const int* __restrict__ bsum,
                                  int* __restrict__ rowstart, int* __restrict__ fillpos,
                                  int N, int E) {
    __shared__ int sdata[256];
    int t = threadIdx.x;
    int i = blockIdx.x * 256 + t;
    int v = (i < N) ? cnt[i] : 0;
    sdata[t] = v;
    __syncthreads();
    for (int off = 1; off < 256; off <<= 1) {
        int u = (t >= off) ? sdata[t - off] : 0;
        __syncthreads();
        sdata[t] += u;
        __syncthreads();
    }
    if (i < N) {
        int r = bsum[blockIdx.x] + sdata[t] - v;   // global exclusive prefix
        rowstart[i] = r;
        fillpos[i]  = r;
    }
    if (i == 0) rowstart[N] = E;
}

__global__ void fill_kernel(const int* __restrict__ src, const int* __restrict__ dst,
                            int* __restrict__ fillpos, int* __restrict__ col, int E) {
    int i = blockIdx.x * blockDim.x + threadIdx.x;
    if (i < E) {
        int p = atomicAdd(&fillpos[dst[i]], 1);
        col[p] = src[i];
    }
}

// ---------------- mean aggregation (one wave per node) ----------------

__global__ __launch_bounds__(64) void agg128_kernel(const float* __restrict__ feat,
                                                    const int* __restrict__ rowstart,
                                                    const int* __restrict__ col,
                                                    float* __restrict__ out) {
    int n = blockIdx.x;
    int t = threadIdx.x;              // 64 threads, float2 each -> 128 feats
    int s = rowstart[n], e = rowstart[n + 1];
    float ax = 0.f, ay = 0.f;
    for (int j = s; j < e; ++j) {
        int c = col[j];
        float2 v = *reinterpret_cast<const float2*>(feat + (size_t)c * F_IN + t * 2);
        ax += v.x; ay += v.y;
    }
    float inv = 1.0f / (float)max(e - s, 1);
    float2 r; r.x = ax * inv; r.y = ay * inv;
    *reinterpret_cast<float2*>(out + (size_t)n * F_IN + t * 2) = r;
}

__global__ __launch_bounds__(64) void agg256_kernel(const float* __restrict__ feat,
                                                    const int* __restrict__ rowstart,
                                                    const int* __restrict__ col,
                                                    float* __restrict__ out) {
    int n = blockIdx.x;
    int t = threadIdx.x;              // 64 threads, float4 each -> 256 feats
    int s = rowstart[n], e = rowstart[n + 1];
    float a0 = 0.f, a1 = 0.f, a2 = 0.f, a3 = 0.f;
    for (int j = s; j < e; ++j) {
        int c = col[j];
        float4 v = *reinterpret_cast<const float4*>(feat + (size_t)c * HID + t * 4);
        a0 += v.x; a1 += v.y; a2 += v.z; a3 += v.w;
    }
    float inv = 1.0f / (float)max(e - s, 1);
    float4 r; r.x = a0 * inv; r.y = a1 * inv; r.z = a2 * inv; r.w = a3 * inv;
    *reinterpret_cast<float4*>(out + (size_t)n * HID + t * 4) = r;
}

// ---------------- layer 1 GEMM: h = relu([agg|x] @ [W1_l|W1_r].T + b1) ----------------
// M=50000, Ncol=256, K=256 (first 128 from agg, last 128 from x)

__global__ __launch_bounds__(256) void gemm1_kernel(const float* __restrict__ agg,
                                                    const float* __restrict__ x,
                                                    const float* __restrict__ Wl,
                                                    const float* __restrict__ Wr,
                                                    const float* __restrict__ bias,
                                                    float* __restrict__ hout, int M) {
    __shared__ float As[16][68];   // k-major, pad 68 (float4-aligned, 2-way conflict only)
    __shared__ float Bs[16][68];
    const int t  = threadIdx.x;
    const int tx = t & 15, ty = t >> 4;
    const int bm = blockIdx.x * 64;
    const int bn = blockIdx.y * 64;
    float acc[4][4] = {};

    for (int kt = 0; kt < 16; ++kt) {
        const float* Asrc = (kt < 8) ? agg : x;
        const float* Bsrc = (kt < 8) ? Wl  : Wr;
        const int kbase = (kt & 7) * 16;
#pragma unroll
        for (int i = 0; i < 4; ++i) {
            int l = t + i * 256;
            int r = l >> 4, k = l & 15;
            int row = bm + r;
            As[k][r] = (row < M) ? Asrc[(size_t)row * F_IN + kbase + k] : 0.f;
        }
#pragma unroll
        for (int i = 0; i < 4; ++i) {
            int l = t + i * 256;
            int n = l >> 4, k = l & 15;
            Bs[k][n] = Bsrc[(size_t)(bn + n) * F_IN + kbase + k];
        }
        __syncthreads();
#pragma unroll
        for (int k = 0; k < 16; ++k) {
            const float4 a4 = *reinterpret_cast<const float4*>(&As[k][ty * 4]);
            const float4 b4 = *reinterpret_cast<const float4*>(&Bs[k][tx * 4]);
            const float av[4] = {a4.x, a4.y, a4.z, a4.w};
            const float bv[4] = {b4.x, b4.y, b4.z, b4.w};
#pragma unroll
            for (int i = 0; i < 4; ++i)
#pragma unroll
                for (int j = 0; j < 4; ++j)
                    acc[i][j] = fmaf(av[i], bv[j], acc[i][j]);
        }
        __syncthreads();
    }
#pragma unroll
    for (int i = 0; i < 4; ++i) {
        int row = bm + ty * 4 + i;
        if (row < M) {
#pragma unroll
            for (int j = 0; j < 4; ++j) {
                int c = bn + tx * 4 + j;
                float v = acc[i][j] + bias[c];
                hout[(size_t)row * HID + c] = fmaxf(v, 0.f);
            }
        }
    }
}

// ---------------- weight pack for layer 2: Wcat[40][512] = [W2_l | W2_r] ----------------

__global__ void pack_w2_kernel(const float* __restrict__ Wl, const float* __restrict__ Wr,
                               float* __restrict__ Wcat) {
    int i = blockIdx.x * 256 + threadIdx.x;
    if (i < NCLS * 512) {
        int c = i >> 9, k = i & 511;
        Wcat[i] = (k < HID) ? Wl[c * HID + k] : Wr[c * HID + (k - HID)];
    }
}

// ---------------- layer 2 GEMM: out = [agg2|h] @ Wcat.T + b2 ----------------
// one row per thread, acc[40], W tile staged in LDS (broadcast reads)

__global__ __launch_bounds__(256) void gemm2_kernel(const float* __restrict__ agg2,
                                                    const float* __restrict__ h,
                                                    const float* __restrict__ Wcat,
                                                    const float* __restrict__ bias,
                                                    float* __restrict__ out, int M) {
    __shared__ float Ws[NCLS][16];
    const int t = threadIdx.x;
    const int row = blockIdx.x * 256 + t;
    float acc[NCLS] = {};

    for (int kt = 0; kt < 32; ++kt) {
        const float* Asrc = (kt < 16) ? agg2 : h;
        const int kb = (kt & 15) * 16;
        // stage W tile: 40x16 = 640 elems
        for (int l = t; l < NCLS * 16; l += 256) {
            int c = l >> 4, k = l & 15;
            Ws[c][k] = Wcat[c * 512 + kt * 16 + k];
        }
        __syncthreads();
        float a[16];
        if (row < M) {
            const float4* p4 = reinterpret_cast<const float4*>(Asrc + (size_t)row * HID + kb);
            float4 v0 = p4[0], v1 = p4[1], v2 = p4[2], v3 = p4[3];
            a[0]=v0.x; a[1]=v0.y; a[2]=v0.z; a[3]=v0.w;
            a[4]=v1.x; a[5]=v1.y; a[6]=v1.z; a[7]=v1.w;
            a[8]=v2.x; a[9]=v2.y; a[10]=v2.z; a[11]=v2.w;
            a[12]=v3.x; a[13]=v3.y; a[14]=v3.z; a[15]=v3.w;
        } else {
#pragma unroll
            for (int k = 0; k < 16; ++k) a[k] = 0.f;
        }
#pragma unroll
        for (int c = 0; c < NCLS; ++c) {
            const float4* w4 = reinterpret_cast<const float4*>(&Ws[c][0]);
            float4 w0 = w4[0], w1 = w4[1], w2 = w4[2], w3 = w4[3];
            acc[c] = fmaf(a[0],  w0.x, acc[c]); acc[c] = fmaf(a[1],  w0.y, acc[c]);
            acc[c] = fmaf(a[2],  w0.z, acc[c]); acc[c] = fmaf(a[3],  w0.w, acc[c]);
            acc[c] = fmaf(a[4],  w1.x, acc[c]); acc[c] = fmaf(a[5],  w1.y, acc[c]);
            acc[c] = fmaf(a[6],  w1.z, acc[c]); acc[c] = fmaf(a[7],  w1.w, acc[c]);
            acc[c] = fmaf(a[8],  w2.x, acc[c]); acc[c] = fmaf(a[9],  w2.y, acc[c]);
            acc[c] = fmaf(a[10], w2.z, acc[c]); acc[c] = fmaf(a[11], w2.w, acc[c]);
            acc[c] = fmaf(a[12], w3.x, acc[c]); acc[c] = fmaf(a[13], w3.y, acc[c]);
            acc[c] = fmaf(a[14], w3.z, acc[c]); acc[c] = fmaf(a[15], w3.w, acc[c]);
        }
        __syncthreads();
    }
    if (row < M) {
#pragma unroll
        for (int c = 0; c < NCLS; ++c)
            out[(size_t)row * NCLS + c] = acc[c] + bias[c];
    }
}

// ---------------- log_softmax in place on d_out (one wave per row) ----------------

__global__ __launch_bounds__(256) void logsoftmax_kernel(float* __restrict__ out, int M) {
    int wid  = threadIdx.x >> 6;
    int lane = threadIdx.x & 63;
    int row  = blockIdx.x * 4 + wid;
    if (row >= M) return;
    float v = (lane < NCLS) ? out[(size_t)row * NCLS + lane] : -INFINITY;
    float m = v;
    for (int off = 32; off; off >>= 1) m = fmaxf(m, __shfl_xor(m, off));
    float ex = (lane < NCLS) ? expf(v - m) : 0.f;
    float s = ex;
    for (int off = 32; off; off >>= 1) s += __shfl_xor(s, off);
    if (lane < NCLS) out[(size_t)row * NCLS + lane] = (v - m) - logf(s);
}

// ---------------- launch ----------------

static inline size_t align256(size_t x) { return (x + 255) & ~(size_t)255; }

extern "C" void kernel_launch(void* const* d_in, const int* in_sizes, int n_in,
                              void* d_out, int out_size, void* d_ws, size_t ws_size,
                              hipStream_t stream) {
    const float* x    = (const float*)d_in[0];
    const int*   ei   = (const int*)d_in[1];
    const float* W1l  = (const float*)d_in[2];
    const float* b1   = (const float*)d_in[3];
    const float* W1r  = (const float*)d_in[4];
    const float* W2l  = (const float*)d_in[5];
    const float* b2   = (const float*)d_in[6];
    const float* W2r  = (const float*)d_in[7];
    float* out = (float*)d_out;

    const int N = N_NODES;
    const int E = in_sizes[1] / 2;
    const int* srcArr = ei;
    const int* dstArr = ei + E;

    // workspace carve-up
    char* ws = (char*)d_ws;
    size_t off = 0;
    auto alloc = [&](size_t bytes) { size_t o = off; off = align256(off + bytes); return o; };
    int*   cnt      = (int*)(ws + alloc((size_t)N * 4));
    int*   rowstart = (int*)(ws + alloc((size_t)(N + 1) * 4));
    int*   fillpos  = (int*)(ws + alloc((size_t)N * 4));
    int*   col      = (int*)(ws + alloc((size_t)E * 4));
    int*   bsum     = (int*)(ws + alloc(1024 * 4));
    float* Wcat     = (float*)(ws + alloc((size_t)NCLS * 512 * 4));
    float* aggbuf   = (float*)(ws + alloc((size_t)N * HID * 4));  // [N,128] for L1, [N,256] for L2
    float* hbuf     = (float*)(ws + alloc((size_t)N * HID * 4));
    (void)ws_size; (void)n_in; (void)out_size;

    const int nbE = (E + 255) / 256;
    const int nbN = (N + 255) / 256;   // 196

    // CSR build
    hipMemsetAsync(cnt, 0, (size_t)N * 4, stream);
    count_kernel<<<nbE, 256, 0, stream>>>(dstArr, cnt, E);
    block_sum_kernel<<<nbN, 256, 0, stream>>>(cnt, bsum, N);
    scan_bsum_kernel<<<1, 1024, 0, stream>>>(bsum, nbN);
    scan_final_kernel<<<nbN, 256, 0, stream>>>(cnt, bsum, rowstart, fillpos, N, E);
    fill_kernel<<<nbE, 256, 0, stream>>>(srcArr, dstArr, fillpos, col, E);

    // weight pack (any time before gemm2)
    pack_w2_kernel<<<(NCLS * 512 + 255) / 256, 256, 0, stream>>>(W2l, W2r, Wcat);

    // layer 1
    agg128_kernel<<<N, 64, 0, stream>>>(x, rowstart, col, aggbuf);
    gemm1_kernel<<<dim3((N + 63) / 64, HID / 64), 256, 0, stream>>>(aggbuf, x, W1l, W1r, b1, hbuf, N);

    // layer 2
    agg256_kernel<<<N, 64, 0, stream>>>(hbuf, rowstart, col, aggbuf);
    gemm2_kernel<<<nbN, 256, 0, stream>>>(aggbuf, hbuf, Wcat, b2, out, N);

    // log_softmax
    logsoftmax_kernel<<<(N + 3) / 4, 256, 0, stream>>>(out, N);
}

// Round 2
// 257.361 us; speedup vs baseline: 1.8471x; 1.8471x over previous
//
#include <hip/hip_runtime.h>
#include <math.h>

#define N_NODES 50000
#define NPAD    50048      // 391 * 128
#define F_IN    128
#define HID     256
#define NCLS    40

typedef __attribute__((ext_vector_type(8))) short bf16x8;
typedef __attribute__((ext_vector_type(4))) float f32x4;

__device__ inline ushort f2bf(float f) {
    uint u = __builtin_bit_cast(uint, f);
    u += 0x7FFF + ((u >> 16) & 1);          // round-to-nearest-even
    return (ushort)(u >> 16);
}
__device__ inline float bf2f(uint h16) {
    uint u = h16 << 16;
    return __builtin_bit_cast(float, u);
}

// ---------------- CSR build ----------------

__global__ void count_kernel(const int* __restrict__ dst, int* __restrict__ cnt, int E) {
    int i = blockIdx.x * blockDim.x + threadIdx.x;
    if (i < E) atomicAdd(&cnt[dst[i]], 1);
}

__global__ void block_sum_kernel(const int* __restrict__ cnt, int* __restrict__ bsum, int N) {
    __shared__ int sdata[256];
    int i = blockIdx.x * 256 + threadIdx.x;
    sdata[threadIdx.x] = (i < N) ? cnt[i] : 0;
    __syncthreads();
    for (int off = 128; off; off >>= 1) {
        if (threadIdx.x < off) sdata[threadIdx.x] += sdata[threadIdx.x + off];
        __syncthreads();
    }
    if (threadIdx.x == 0) bsum[blockIdx.x] = sdata[0];
}

__global__ void scan_bsum_kernel(int* bsum, int nb) {
    __shared__ int sdata[1024];
    int t = threadIdx.x;
    int v = (t < nb) ? bsum[t] : 0;
    sdata[t] = v;
    __syncthreads();
    for (int off = 1; off < 1024; off <<= 1) {
        int u = (t >= off) ? sdata[t - off] : 0;
        __syncthreads();
        sdata[t] += u;
        __syncthreads();
    }
    if (t < nb) bsum[t] = sdata[t] - v;   // exclusive
}

__global__ void scan_final_kernel(const int* __restrict__ cnt, const int* __restrict__ bsum,
                                  int* __restrict__ rowstart, int* __restrict__ fillpos,
                                  int N, int E) {
    __shared__ int sdata[256];
    int t = threadIdx.x;
    int i = blockIdx.x * 256 + t;
    int v = (i < N) ? cnt[i] : 0;
    sdata[t] = v;
    __syncthreads();
    for (int off = 1; off < 256; off <<= 1) {
        int u = (t >= off) ? sdata[t - off] : 0;
        __syncthreads();
        sdata[t] += u;
        __syncthreads();
    }
    if (i < N) {
        int r = bsum[blockIdx.x] + sdata[t] - v;
        rowstart[i] = r;
        fillpos[i]  = r;
    }
    if (i == 0) rowstart[N] = E;
}

__global__ void fill_kernel(const int* __restrict__ src, const int* __restrict__ dst,
                            int* __restrict__ fillpos, int* __restrict__ col, int E) {
    int i = blockIdx.x * blockDim.x + threadIdx.x;
    if (i < E) {
        int p = atomicAdd(&fillpos[dst[i]], 1);
        col[p] = src[i];
    }
}

// ---------------- casts / weight packs ----------------

__global__ void cast_x_kernel(const float* __restrict__ x, ushort* __restrict__ xb, int n4) {
    int i = blockIdx.x * 256 + threadIdx.x;
    if (i < n4) {
        float4 v = *reinterpret_cast<const float4*>(x + (size_t)i * 4);
        ushort4 o;
        o.x = f2bf(v.x); o.y = f2bf(v.y); o.z = f2bf(v.z); o.w = f2bf(v.w);
        *reinterpret_cast<ushort4*>(xb + (size_t)i * 4) = o;
    }
}

// Wb1[256][256] = [W1_l | W1_r] rows=out-col, bf16
__global__ void pack_w1_kernel(const float* __restrict__ Wl, const float* __restrict__ Wr,
                               ushort* __restrict__ Wb) {
    int i = blockIdx.x * 256 + threadIdx.x;   // 65536
    int n = i >> 8, k = i & 255;
    float v = (k < 128) ? Wl[n * 128 + k] : Wr[n * 128 + (k - 128)];
    Wb[i] = f2bf(v);
}

// Wb2[80][256]: rows 0-39 = W2_l, rows 40-79 = W2_r
__global__ void pack_w2_kernel(const float* __restrict__ Wl, const float* __restrict__ Wr,
                               ushort* __restrict__ Wb) {
    int i = blockIdx.x * 256 + threadIdx.x;   // 20480
    int n = i >> 8, k = i & 255;
    float v = (n < 40) ? Wl[n * 256 + k] : Wr[(n - 40) * 256 + k];
    Wb[i] = f2bf(v);
}

// ---------------- mean aggregation layer 1 (bf16 in/out, fp32 accum) ----------------

__global__ __launch_bounds__(256) void agg128_kernel(const ushort* __restrict__ xb,
                                                     const int* __restrict__ rowstart,
                                                     const int* __restrict__ col,
                                                     ushort* __restrict__ aggb) {
    int wid = threadIdx.x >> 6, l = threadIdx.x & 63;
    int n = blockIdx.x * 4 + wid;
    if (n >= N_NODES) return;
    int s = rowstart[n], e = rowstart[n + 1];
    float ax = 0.f, ay = 0.f;
    for (int j = s; j < e; ++j) {
        int c = col[j];
        uint v = *reinterpret_cast<const uint*>(xb + (size_t)c * F_IN + l * 2);
        ax += bf2f(v & 0xffffu);
        ay += bf2f(v >> 16);
    }
    float inv = 1.0f / (float)max(e - s, 1);
    uint o = (uint)f2bf(ax * inv) | ((uint)f2bf(ay * inv) << 16);
    *reinterpret_cast<uint*>(aggb + (size_t)n * F_IN + l * 2) = o;
}

// ---------------- GEMM1: hb = relu([aggb|xb] @ Wb1.T + b1), bf16 out ----------------
// M=NPAD, N=256 (blockIdx.y in {0,1}), K=256. Full 128x256 B-panel in LDS, XOR-swizzled.

__global__ __launch_bounds__(256) void gemm1_kernel(const ushort* __restrict__ aggb,
                                                    const ushort* __restrict__ xb,
                                                    const ushort* __restrict__ Wb1,
                                                    const float* __restrict__ b1,
                                                    ushort* __restrict__ hb) {
    __shared__ __align__(16) char Bls[128 * 512];   // 64 KiB
    const int t = threadIdx.x, w = t >> 6, l = t & 63;
    const int bm = blockIdx.x * 128, bn = blockIdx.y * 128;

    // stage B (128 rows x 256 k bf16), swizzle: byte ^= (row&7)<<4
    for (int i = t; i < 128 * 32; i += 256) {
        int n = i >> 5, k8 = (i & 31) * 8;
        uint4 v = *reinterpret_cast<const uint4*>(Wb1 + (size_t)(bn + n) * 256 + k8);
        *reinterpret_cast<uint4*>(Bls + ((n * 512 + k8 * 2) ^ ((n & 7) << 4))) = v;
    }
    __syncthreads();

    const int lr = l & 15, lg = l >> 4;
    f32x4 acc[2][8] = {};
#pragma unroll
    for (int kt = 0; kt < 8; ++kt) {
        const ushort* Ap = (kt < 4) ? aggb : xb;
        int kb = kt * 32 - ((kt < 4) ? 0 : 128) + lg * 8;
        bf16x8 a0 = *reinterpret_cast<const bf16x8*>(Ap + (size_t)(bm + w * 32 + lr) * F_IN + kb);
        bf16x8 a1 = *reinterpret_cast<const bf16x8*>(Ap + (size_t)(bm + w * 32 + 16 + lr) * F_IN + kb);
        int kbyte = kt * 64 + lg * 16;
#pragma unroll
        for (int j = 0; j < 8; ++j) {
            int nl = j * 16 + lr;
            bf16x8 b = *reinterpret_cast<const bf16x8*>(Bls + ((nl * 512 + kbyte) ^ ((nl & 7) << 4)));
            acc[0][j] = __builtin_amdgcn_mfma_f32_16x16x32_bf16(a0, b, acc[0][j], 0, 0, 0);
            acc[1][j] = __builtin_amdgcn_mfma_f32_16x16x32_bf16(a1, b, acc[1][j], 0, 0, 0);
        }
    }
    // epilogue: D layout col=lane&15, row=(lane>>4)*4+r  [m89-verified]
#pragma unroll
    for (int m = 0; m < 2; ++m) {
        int rbase = bm + w * 32 + m * 16 + lg * 4;
#pragma unroll
        for (int j = 0; j < 8; ++j) {
            int c = bn + j * 16 + lr;
            float bias = b1[c];
#pragma unroll
            for (int r = 0; r < 4; ++r) {
                float v = acc[m][j][r] + bias;
                hb[(size_t)(rbase + r) * HID + c] = f2bf(fmaxf(v, 0.f));
            }
        }
    }
}

// ---------------- GEMM2: [hW | out_r] = hb @ Wb2.T ----------------
// N=80: cols 0-39 -> hWb (bf16, no bias); cols 40-79 -> d_out fp32 (+b2)

__global__ __launch_bounds__(256) void gemm2_kernel(const ushort* __restrict__ hb,
                                                    const ushort* __restrict__ Wb2,
                                                    const float* __restrict__ b2,
                                                    ushort* __restrict__ hWb,
                                                    float* __restrict__ outp) {
    __shared__ __align__(16) char Bls[80 * 512];   // 40 KiB
    const int t = threadIdx.x, w = t >> 6, l = t & 63;
    const int bm = blockIdx.x * 128;

    for (int i = t; i < 80 * 32; i += 256) {
        int n = i >> 5, k8 = (i & 31) * 8;
        uint4 v = *reinterpret_cast<const uint4*>(Wb2 + (size_t)n * 256 + k8);
        *reinterpret_cast<uint4*>(Bls + ((n * 512 + k8 * 2) ^ ((n & 7) << 4))) = v;
    }
    __syncthreads();

    const int lr = l & 15, lg = l >> 4;
    f32x4 acc[2][5] = {};
#pragma unroll
    for (int kt = 0; kt < 8; ++kt) {
        int kb = kt * 32 + lg * 8;
        bf16x8 a0 = *reinterpret_cast<const bf16x8*>(hb + (size_t)(bm + w * 32 + lr) * HID + kb);
        bf16x8 a1 = *reinterpret_cast<const bf16x8*>(hb + (size_t)(bm + w * 32 + 16 + lr) * HID + kb);
        int kbyte = kt * 64 + lg * 16;
#pragma unroll
        for (int j = 0; j < 5; ++j) {
            int nl = j * 16 + lr;
            bf16x8 b = *reinterpret_cast<const bf16x8*>(Bls + ((nl * 512 + kbyte) ^ ((nl & 7) << 4)));
            acc[0][j] = __builtin_amdgcn_mfma_f32_16x16x32_bf16(a0, b, acc[0][j], 0, 0, 0);
            acc[1][j] = __builtin_amdgcn_mfma_f32_16x16x32_bf16(a1, b, acc[1][j], 0, 0, 0);
        }
    }
#pragma unroll
    for (int m = 0; m < 2; ++m) {
        int rbase = bm + w * 32 + m * 16 + lg * 4;
#pragma unroll
        for (int j = 0; j < 5; ++j) {
            int cfull = j * 16 + lr;
#pragma unroll
            for (int r = 0; r < 4; ++r) {
                int row = rbase + r;
                float v = acc[m][j][r];
                if (cfull < 40) {
                    hWb[(size_t)row * NCLS + cfull] = f2bf(v);   // hWb padded to NPAD rows
                } else if (row < N_NODES) {
                    int c = cfull - 40;
                    outp[(size_t)row * NCLS + c] = v + b2[c];
                }
            }
        }
    }
}

// ---------------- fused: out = log_softmax(out_partial + mean_j hW_j) ----------------

__global__ __launch_bounds__(256) void agg40_lsm_kernel(const ushort* __restrict__ hWb,
                                                        const int* __restrict__ rowstart,
                                                        const int* __restrict__ col,
                                                        float* __restrict__ out) {
    int wid = threadIdx.x >> 6, l = threadIdx.x & 63;
    int n = blockIdx.x * 4 + wid;
    if (n >= N_NODES) return;
    int s = rowstart[n], e = rowstart[n + 1];
    bool act = l < 20;                       // lanes 0-19 own 2 classes each
    float a0 = 0.f, a1 = 0.f;
    for (int j = s; j < e; ++j) {
        int c = col[j];
        if (act) {
            uint v = *reinterpret_cast<const uint*>(hWb + (size_t)c * NCLS + l * 2);
            a0 += bf2f(v & 0xffffu);
            a1 += bf2f(v >> 16);
        }
    }
    float inv = 1.0f / (float)max(e - s, 1);
    float v0 = -INFINITY, v1 = -INFINITY;
    if (act) {
        float2 p = *reinterpret_cast<const float2*>(out + (size_t)n * NCLS + l * 2);
        v0 = p.x + a0 * inv;
        v1 = p.y + a1 * inv;
    }
    float m = fmaxf(v0, v1);
    for (int off = 32; off; off >>= 1) m = fmaxf(m, __shfl_xor(m, off));
    float ex = act ? (expf(v0 - m) + expf(v1 - m)) : 0.f;
    float ssum = ex;
    for (int off = 32; off; off >>= 1) ssum += __shfl_xor(ssum, off);
    float ls = logf(ssum);
    if (act) {
        float2 o;
        o.x = v0 - m - ls;
        o.y = v1 - m - ls;
        *reinterpret_cast<float2*>(out + (size_t)n * NCLS + l * 2) = o;
    }
}

// ---------------- launch ----------------

static inline size_t align256(size_t x) { return (x + 255) & ~(size_t)255; }

extern "C" void kernel_launch(void* const* d_in, const int* in_sizes, int n_in,
                              void* d_out, int out_size, void* d_ws, size_t ws_size,
                              hipStream_t stream) {
    const float* x    = (const float*)d_in[0];
    const int*   ei   = (const int*)d_in[1];
    const float* W1l  = (const float*)d_in[2];
    const float* b1   = (const float*)d_in[3];
    const float* W1r  = (const float*)d_in[4];
    const float* W2l  = (const float*)d_in[5];
    const float* b2   = (const float*)d_in[6];
    const float* W2r  = (const float*)d_in[7];
    float* out = (float*)d_out;

    const int N = N_NODES;
    const int E = in_sizes[1] / 2;
    const int* srcArr = ei;
    const int* dstArr = ei + E;

    char* ws = (char*)d_ws;
    size_t off = 0;
    auto alloc = [&](size_t bytes) { size_t o = off; off = align256(off + bytes); return o; };
    int*    cnt      = (int*)(ws + alloc((size_t)N * 4));
    int*    rowstart = (int*)(ws + alloc((size_t)(N + 1) * 4));
    int*    fillpos  = (int*)(ws + alloc((size_t)N * 4));
    int*    col      = (int*)(ws + alloc((size_t)E * 4));
    int*    bsum     = (int*)(ws + alloc(1024 * 4));
    ushort* xb       = (ushort*)(ws + alloc((size_t)NPAD * F_IN * 2));
    ushort* aggb     = (ushort*)(ws + alloc((size_t)NPAD * F_IN * 2));
    ushort* hb       = (ushort*)(ws + alloc((size_t)NPAD * HID * 2));
    ushort* hWb      = (ushort*)(ws + alloc((size_t)NPAD * NCLS * 2));
    ushort* Wb1      = (ushort*)(ws + alloc((size_t)256 * 256 * 2));
    ushort* Wb2      = (ushort*)(ws + alloc((size_t)80 * 256 * 2));
    (void)ws_size; (void)n_in; (void)out_size;

    const int nbE = (E + 255) / 256;
    const int nbN = (N + 255) / 256;   // 196

    // CSR build
    hipMemsetAsync(cnt, 0, (size_t)N * 4, stream);
    count_kernel<<<nbE, 256, 0, stream>>>(dstArr, cnt, E);
    block_sum_kernel<<<nbN, 256, 0, stream>>>(cnt, bsum, N);
    scan_bsum_kernel<<<1, 1024, 0, stream>>>(bsum, nbN);
    scan_final_kernel<<<nbN, 256, 0, stream>>>(cnt, bsum, rowstart, fillpos, N, E);
    fill_kernel<<<nbE, 256, 0, stream>>>(srcArr, dstArr, fillpos, col, E);

    // casts / packs
    cast_x_kernel<<<(N * F_IN / 4 + 255) / 256, 256, 0, stream>>>(x, xb, N * F_IN / 4);
    pack_w1_kernel<<<256, 256, 0, stream>>>(W1l, W1r, Wb1);
    pack_w2_kernel<<<80, 256, 0, stream>>>(W2l, W2r, Wb2);

    // layer 1
    agg128_kernel<<<(N + 3) / 4, 256, 0, stream>>>(xb, rowstart, col, aggb);
    gemm1_kernel<<<dim3(NPAD / 128, 2), 256, 0, stream>>>(aggb, xb, Wb1, b1, hb);

    // layer 2 (transform-then-aggregate)
    gemm2_kernel<<<NPAD / 128, 256, 0, stream>>>(hb, Wb2, b2, hWb, out);
    agg40_lsm_kernel<<<(N + 3) / 4, 256, 0, stream>>>(hWb, rowstart, col, out);
}

// Round 3
// 190.203 us; speedup vs baseline: 2.4993x; 1.3531x over previous
//
#include <hip/hip_runtime.h>
#include <math.h>

#define N_NODES 50000
#define NPAD    50048      // 391 * 128
#define F_IN    128
#define HID     256
#define NCLS    40
#define WPAD    64         // padded hW width

typedef __attribute__((ext_vector_type(8))) short bf16x8;
typedef __attribute__((ext_vector_type(4))) float f32x4;

__device__ inline ushort f2bf(float f) {
    uint u = __builtin_bit_cast(uint, f);
    u += 0x7FFF + ((u >> 16) & 1);          // round-to-nearest-even
    return (ushort)(u >> 16);
}
__device__ inline float bf2f(uint h16) {
    uint u = h16 << 16;
    return __builtin_bit_cast(float, u);
}

// ---------------- CSR build ----------------

__global__ void count_kernel(const int* __restrict__ dst, int* __restrict__ cnt, int E) {
    int i = blockIdx.x * blockDim.x + threadIdx.x;
    if (i < E) atomicAdd(&cnt[dst[i]], 1);
}

__global__ void block_sum_kernel(const int* __restrict__ cnt, int* __restrict__ bsum, int N) {
    __shared__ int sdata[256];
    int i = blockIdx.x * 256 + threadIdx.x;
    sdata[threadIdx.x] = (i < N) ? cnt[i] : 0;
    __syncthreads();
    for (int off = 128; off; off >>= 1) {
        if (threadIdx.x < off) sdata[threadIdx.x] += sdata[threadIdx.x + off];
        __syncthreads();
    }
    if (threadIdx.x == 0) bsum[blockIdx.x] = sdata[0];
}

__global__ void scan_bsum_kernel(int* bsum, int nb) {
    __shared__ int sdata[1024];
    int t = threadIdx.x;
    int v = (t < nb) ? bsum[t] : 0;
    sdata[t] = v;
    __syncthreads();
    for (int off = 1; off < 1024; off <<= 1) {
        int u = (t >= off) ? sdata[t - off] : 0;
        __syncthreads();
        sdata[t] += u;
        __syncthreads();
    }
    if (t < nb) bsum[t] = sdata[t] - v;   // exclusive
}

__global__ void scan_final_kernel(const int* __restrict__ cnt, const int* __restrict__ bsum,
                                  int* __restrict__ rowstart, int* __restrict__ fillpos,
                                  int N, int E) {
    __shared__ int sdata[256];
    int t = threadIdx.x;
    int i = blockIdx.x * 256 + t;
    int v = (i < N) ? cnt[i] : 0;
    sdata[t] = v;
    __syncthreads();
    for (int off = 1; off < 256; off <<= 1) {
        int u = (t >= off) ? sdata[t - off] : 0;
        __syncthreads();
        sdata[t] += u;
        __syncthreads();
    }
    if (i < N) {
        int r = bsum[blockIdx.x] + sdata[t] - v;
        rowstart[i] = r;
        fillpos[i]  = r;
    }
    if (i == 0) rowstart[N] = E;
}

__global__ void fill_kernel(const int* __restrict__ src, const int* __restrict__ dst,
                            int* __restrict__ fillpos, int* __restrict__ col, int E) {
    int i = blockIdx.x * blockDim.x + threadIdx.x;
    if (i < E) {
        int p = atomicAdd(&fillpos[dst[i]], 1);
        col[p] = src[i];
    }
}

// ---------------- casts / weight packs ----------------

__global__ void cast_x_kernel(const float* __restrict__ x, ushort* __restrict__ xb, int n4) {
    int i = blockIdx.x * 256 + threadIdx.x;
    if (i < n4) {
        float4 v = *reinterpret_cast<const float4*>(x + (size_t)i * 4);
        ushort4 o;
        o.x = f2bf(v.x); o.y = f2bf(v.y); o.z = f2bf(v.z); o.w = f2bf(v.w);
        *reinterpret_cast<ushort4*>(xb + (size_t)i * 4) = o;
    }
}

// Wb1[256][256] = [W1_l | W1_r] rows=out-col, bf16
__global__ void pack_w1_kernel(const float* __restrict__ Wl, const float* __restrict__ Wr,
                               ushort* __restrict__ Wb) {
    int i = blockIdx.x * 256 + threadIdx.x;   // 65536
    int n = i >> 8, k = i & 255;
    float v = (k < 128) ? Wl[n * 128 + k] : Wr[n * 128 + (k - 128)];
    Wb[i] = f2bf(v);
}

// Wb2[80][256]: rows 0-39 = W2_l, rows 40-79 = W2_r
__global__ void pack_w2_kernel(const float* __restrict__ Wl, const float* __restrict__ Wr,
                               ushort* __restrict__ Wb) {
    int i = blockIdx.x * 256 + threadIdx.x;   // 20480
    int n = i >> 8, k = i & 255;
    float v = (n < 40) ? Wl[n * 256 + k] : Wr[(n - 40) * 256 + k];
    Wb[i] = f2bf(v);
}

// ---------------- mean aggregation layer 1 ----------------
// 4 edges in flight per wave: 4 groups x 16 lanes x 16B

__global__ __launch_bounds__(256) void agg128_kernel(const ushort* __restrict__ xb,
                                                     const int* __restrict__ rowstart,
                                                     const int* __restrict__ col,
                                                     ushort* __restrict__ aggb) {
    int wid = threadIdx.x >> 6, l = threadIdx.x & 63;
    int n = blockIdx.x * 4 + wid;
    if (n >= N_NODES) return;
    int g = l >> 4, lr = l & 15;
    int s = rowstart[n], e = rowstart[n + 1];
    float a[8] = {};
    for (int j = s + g; j < e; j += 4) {
        int c = col[j];
        uint4 v = *reinterpret_cast<const uint4*>(xb + (size_t)c * F_IN + lr * 8);
        a[0] += bf2f(v.x & 0xffffu); a[1] += bf2f(v.x >> 16);
        a[2] += bf2f(v.y & 0xffffu); a[3] += bf2f(v.y >> 16);
        a[4] += bf2f(v.z & 0xffffu); a[5] += bf2f(v.z >> 16);
        a[6] += bf2f(v.w & 0xffffu); a[7] += bf2f(v.w >> 16);
    }
#pragma unroll
    for (int i = 0; i < 8; ++i) {
        a[i] += __shfl_xor(a[i], 16);
        a[i] += __shfl_xor(a[i], 32);
    }
    if (g == 0) {
        float inv = 1.0f / (float)max(e - s, 1);
        uint4 o;
        o.x = (uint)f2bf(a[0] * inv) | ((uint)f2bf(a[1] * inv) << 16);
        o.y = (uint)f2bf(a[2] * inv) | ((uint)f2bf(a[3] * inv) << 16);
        o.z = (uint)f2bf(a[4] * inv) | ((uint)f2bf(a[5] * inv) << 16);
        o.w = (uint)f2bf(a[6] * inv) | ((uint)f2bf(a[7] * inv) << 16);
        *reinterpret_cast<uint4*>(aggb + (size_t)n * F_IN + lr * 8) = o;
    }
}

// ---------------- GEMM1: hb = relu([aggb|xb] @ Wb1.T + b1), bf16 out ----------------

__global__ __launch_bounds__(256) void gemm1_kernel(const ushort* __restrict__ aggb,
                                                    const ushort* __restrict__ xb,
                                                    const ushort* __restrict__ Wb1,
                                                    const float* __restrict__ b1,
                                                    ushort* __restrict__ hb) {
    __shared__ __align__(16) char Bls[128 * 512];   // 64 KiB
    const int t = threadIdx.x, w = t >> 6, l = t & 63;
    const int bm = blockIdx.x * 128, bn = blockIdx.y * 128;

    for (int i = t; i < 128 * 32; i += 256) {
        int n = i >> 5, k8 = (i & 31) * 8;
        uint4 v = *reinterpret_cast<const uint4*>(Wb1 + (size_t)(bn + n) * 256 + k8);
        *reinterpret_cast<uint4*>(Bls + ((n * 512 + k8 * 2) ^ ((n & 7) << 4))) = v;
    }
    __syncthreads();

    const int lr = l & 15, lg = l >> 4;
    f32x4 acc[2][8] = {};
#pragma unroll
    for (int kt = 0; kt < 8; ++kt) {
        const ushort* Ap = (kt < 4) ? aggb : xb;
        int kb = kt * 32 - ((kt < 4) ? 0 : 128) + lg * 8;
        bf16x8 a0 = *reinterpret_cast<const bf16x8*>(Ap + (size_t)(bm + w * 32 + lr) * F_IN + kb);
        bf16x8 a1 = *reinterpret_cast<const bf16x8*>(Ap + (size_t)(bm + w * 32 + 16 + lr) * F_IN + kb);
        int kbyte = kt * 64 + lg * 16;
#pragma unroll
        for (int j = 0; j < 8; ++j) {
            int nl = j * 16 + lr;
            bf16x8 b = *reinterpret_cast<const bf16x8*>(Bls + ((nl * 512 + kbyte) ^ ((nl & 7) << 4)));
            acc[0][j] = __builtin_amdgcn_mfma_f32_16x16x32_bf16(a0, b, acc[0][j], 0, 0, 0);
            acc[1][j] = __builtin_amdgcn_mfma_f32_16x16x32_bf16(a1, b, acc[1][j], 0, 0, 0);
        }
    }
#pragma unroll
    for (int m = 0; m < 2; ++m) {
        int rbase = bm + w * 32 + m * 16 + lg * 4;
#pragma unroll
        for (int j = 0; j < 8; ++j) {
            int c = bn + j * 16 + lr;
            float bias = b1[c];
#pragma unroll
            for (int r = 0; r < 4; ++r) {
                float v = acc[m][j][r] + bias;
                hb[(size_t)(rbase + r) * HID + c] = f2bf(fmaxf(v, 0.f));
            }
        }
    }
}

// ---------------- GEMM2: [hW | out_r] = hb @ Wb2.T ----------------
// cols 0-39 -> hWb bf16 (stride WPAD, cols 40-63 zeroed); cols 40-79 -> d_out fp32 (+b2)

__global__ __launch_bounds__(256) void gemm2_kernel(const ushort* __restrict__ hb,
                                                    const ushort* __restrict__ Wb2,
                                                    const float* __restrict__ b2,
                                                    ushort* __restrict__ hWb,
                                                    float* __restrict__ outp) {
    __shared__ __align__(16) char Bls[80 * 512];   // 40 KiB
    const int t = threadIdx.x, w = t >> 6, l = t & 63;
    const int bm = blockIdx.x * 128;

    for (int i = t; i < 80 * 32; i += 256) {
        int n = i >> 5, k8 = (i & 31) * 8;
        uint4 v = *reinterpret_cast<const uint4*>(Wb2 + (size_t)n * 256 + k8);
        *reinterpret_cast<uint4*>(Bls + ((n * 512 + k8 * 2) ^ ((n & 7) << 4))) = v;
    }
    __syncthreads();

    const int lr = l & 15, lg = l >> 4;
    f32x4 acc[2][5] = {};
#pragma unroll
    for (int kt = 0; kt < 8; ++kt) {
        int kb = kt * 32 + lg * 8;
        bf16x8 a0 = *reinterpret_cast<const bf16x8*>(hb + (size_t)(bm + w * 32 + lr) * HID + kb);
        bf16x8 a1 = *reinterpret_cast<const bf16x8*>(hb + (size_t)(bm + w * 32 + 16 + lr) * HID + kb);
        int kbyte = kt * 64 + lg * 16;
#pragma unroll
        for (int j = 0; j < 5; ++j) {
            int nl = j * 16 + lr;
            bf16x8 b = *reinterpret_cast<const bf16x8*>(Bls + ((nl * 512 + kbyte) ^ ((nl & 7) << 4)));
            acc[0][j] = __builtin_amdgcn_mfma_f32_16x16x32_bf16(a0, b, acc[0][j], 0, 0, 0);
            acc[1][j] = __builtin_amdgcn_mfma_f32_16x16x32_bf16(a1, b, acc[1][j], 0, 0, 0);
        }
    }
#pragma unroll
    for (int m = 0; m < 2; ++m) {
        int rbase = bm + w * 32 + m * 16 + lg * 4;
#pragma unroll
        for (int j = 0; j < 5; ++j) {
            int cfull = j * 16 + lr;
#pragma unroll
            for (int r = 0; r < 4; ++r) {
                int row = rbase + r;
                float v = acc[m][j][r];
                if (cfull < 40) {
                    hWb[(size_t)row * WPAD + cfull] = f2bf(v);
                } else {
                    if (cfull < 64) hWb[(size_t)row * WPAD + cfull] = 0;  // zero pad cols
                    if (row < N_NODES) {
                        int c = cfull - 40;
                        outp[(size_t)row * NCLS + c] = v + b2[c];
                    }
                }
            }
        }
    }
}

// ---------------- fused: out = log_softmax(out_partial + mean_j hW_j) ----------------
// 8 edges in flight per wave: 8 groups x 8 lanes x 16B (WPAD=64 bf16 rows)

__global__ __launch_bounds__(256) void agg40_lsm_kernel(const ushort* __restrict__ hWb,
                                                        const int* __restrict__ rowstart,
                                                        const int* __restrict__ col,
                                                        float* __restrict__ out) {
    int wid = threadIdx.x >> 6, l = threadIdx.x & 63;
    int n = blockIdx.x * 4 + wid;
    if (n >= N_NODES) return;
    int g = l >> 3, lr = l & 7;
    int s = rowstart[n], e = rowstart[n + 1];
    float a[8] = {};
    for (int j = s + g; j < e; j += 8) {
        int c = col[j];
        uint4 v = *reinterpret_cast<const uint4*>(hWb + (size_t)c * WPAD + lr * 8);
        a[0] += bf2f(v.x & 0xffffu); a[1] += bf2f(v.x >> 16);
        a[2] += bf2f(v.y & 0xffffu); a[3] += bf2f(v.y >> 16);
        a[4] += bf2f(v.z & 0xffffu); a[5] += bf2f(v.z >> 16);
        a[6] += bf2f(v.w & 0xffffu); a[7] += bf2f(v.w >> 16);
    }
#pragma unroll
    for (int i = 0; i < 8; ++i) {
        a[i] += __shfl_xor(a[i], 8);
        a[i] += __shfl_xor(a[i], 16);
        a[i] += __shfl_xor(a[i], 32);
    }
    // lanes 0-7 (g==0) hold class sums for classes lr*8..lr*8+7; lr<5 valid
    float inv = 1.0f / (float)max(e - s, 1);
    bool act = (g == 0) && (lr < 5);
    float v[8];
    if (act) {
        const float* pb = out + (size_t)n * NCLS + lr * 8;
        float4 p0 = *reinterpret_cast<const float4*>(pb);
        float4 p1 = *reinterpret_cast<const float4*>(pb + 4);
        v[0] = p0.x + a[0] * inv; v[1] = p0.y + a[1] * inv;
        v[2] = p0.z + a[2] * inv; v[3] = p0.w + a[3] * inv;
        v[4] = p1.x + a[4] * inv; v[5] = p1.y + a[5] * inv;
        v[6] = p1.z + a[6] * inv; v[7] = p1.w + a[7] * inv;
    } else {
#pragma unroll
        for (int i = 0; i < 8; ++i) v[i] = -INFINITY;
    }
    float m = v[0];
#pragma unroll
    for (int i = 1; i < 8; ++i) m = fmaxf(m, v[i]);
    m = fmaxf(m, __shfl_xor(m, 1));
    m = fmaxf(m, __shfl_xor(m, 2));
    m = fmaxf(m, __shfl_xor(m, 4));
    float ex = 0.f;
    if (act) {
#pragma unroll
        for (int i = 0; i < 8; ++i) ex += expf(v[i] - m);
    }
    ex += __shfl_xor(ex, 1);
    ex += __shfl_xor(ex, 2);
    ex += __shfl_xor(ex, 4);
    float ls = logf(ex);
    if (act) {
        float* ob = out + (size_t)n * NCLS + lr * 8;
        float4 o0, o1;
        o0.x = v[0] - m - ls; o0.y = v[1] - m - ls; o0.z = v[2] - m - ls; o0.w = v[3] - m - ls;
        o1.x = v[4] - m - ls; o1.y = v[5] - m - ls; o1.z = v[6] - m - ls; o1.w = v[7] - m - ls;
        *reinterpret_cast<float4*>(ob) = o0;
        *reinterpret_cast<float4*>(ob + 4) = o1;
    }
}

// ---------------- launch ----------------

static inline size_t align256(size_t x) { return (x + 255) & ~(size_t)255; }

extern "C" void kernel_launch(void* const* d_in, const int* in_sizes, int n_in,
                              void* d_out, int out_size, void* d_ws, size_t ws_size,
                              hipStream_t stream) {
    const float* x    = (const float*)d_in[0];
    const int*   ei   = (const int*)d_in[1];
    const float* W1l  = (const float*)d_in[2];
    const float* b1   = (const float*)d_in[3];
    const float* W1r  = (const float*)d_in[4];
    const float* W2l  = (const float*)d_in[5];
    const float* b2   = (const float*)d_in[6];
    const float* W2r  = (const float*)d_in[7];
    float* out = (float*)d_out;

    const int N = N_NODES;
    const int E = in_sizes[1] / 2;
    const int* srcArr = ei;
    const int* dstArr = ei + E;

    char* ws = (char*)d_ws;
    size_t off = 0;
    auto alloc = [&](size_t bytes) { size_t o = off; off = align256(off + bytes); return o; };
    int*    cnt      = (int*)(ws + alloc((size_t)N * 4));
    int*    rowstart = (int*)(ws + alloc((size_t)(N + 1) * 4));
    int*    fillpos  = (int*)(ws + alloc((size_t)N * 4));
    int*    col      = (int*)(ws + alloc((size_t)E * 4));
    int*    bsum     = (int*)(ws + alloc(1024 * 4));
    ushort* xb       = (ushort*)(ws + alloc((size_t)NPAD * F_IN * 2));
    ushort* aggb     = (ushort*)(ws + alloc((size_t)NPAD * F_IN * 2));
    ushort* hb       = (ushort*)(ws + alloc((size_t)NPAD * HID * 2));
    ushort* hWb      = (ushort*)(ws + alloc((size_t)NPAD * WPAD * 2));
    ushort* Wb1      = (ushort*)(ws + alloc((size_t)256 * 256 * 2));
    ushort* Wb2      = (ushort*)(ws + alloc((size_t)80 * 256 * 2));
    (void)ws_size; (void)n_in; (void)out_size;

    const int nbE = (E + 255) / 256;
    const int nbN = (N + 255) / 256;

    // CSR build
    hipMemsetAsync(cnt, 0, (size_t)N * 4, stream);
    count_kernel<<<nbE, 256, 0, stream>>>(dstArr, cnt, E);
    block_sum_kernel<<<nbN, 256, 0, stream>>>(cnt, bsum, N);
    scan_bsum_kernel<<<1, 1024, 0, stream>>>(bsum, nbN);
    scan_final_kernel<<<nbN, 256, 0, stream>>>(cnt, bsum, rowstart, fillpos, N, E);
    fill_kernel<<<nbE, 256, 0, stream>>>(srcArr, dstArr, fillpos, col, E);

    // casts / packs; zero pad rows for determinism
    hipMemsetAsync(xb + (size_t)N * F_IN, 0, (size_t)(NPAD - N) * F_IN * 2, stream);
    hipMemsetAsync(aggb + (size_t)N * F_IN, 0, (size_t)(NPAD - N) * F_IN * 2, stream);
    cast_x_kernel<<<(N * F_IN / 4 + 255) / 256, 256, 0, stream>>>(x, xb, N * F_IN / 4);
    pack_w1_kernel<<<256, 256, 0, stream>>>(W1l, W1r, Wb1);
    pack_w2_kernel<<<80, 256, 0, stream>>>(W2l, W2r, Wb2);

    // layer 1
    agg128_kernel<<<(N + 3) / 4, 256, 0, stream>>>(xb, rowstart, col, aggb);
    gemm1_kernel<<<dim3(NPAD / 128, 2), 256, 0, stream>>>(aggb, xb, Wb1, b1, hb);

    // layer 2 (transform-then-aggregate)
    gemm2_kernel<<<NPAD / 128, 256, 0, stream>>>(hb, Wb2, b2, hWb, out);
    agg40_lsm_kernel<<<(N + 3) / 4, 256, 0, stream>>>(hWb, rowstart, col, out);
}

// Round 4
// 185.564 us; speedup vs baseline: 2.5618x; 1.0250x over previous
//
#include <hip/hip_runtime.h>
#include <math.h>

#define N_NODES 50000
#define NPAD    50048      // 391 * 128
#define F_IN    128
#define HID     256
#define NCLS    40
#define WPAD    64         // padded hW width

typedef __attribute__((ext_vector_type(8))) short bf16x8;
typedef __attribute__((ext_vector_type(4))) float f32x4;

__device__ inline ushort f2bf(float f) {
    uint u = __builtin_bit_cast(uint, f);
    u += 0x7FFF + ((u >> 16) & 1);          // round-to-nearest-even
    return (ushort)(u >> 16);
}
__device__ inline float bf2f(uint h16) {
    uint u = h16 << 16;
    return __builtin_bit_cast(float, u);
}

// ---------------- CSR build ----------------

__global__ void zero_cnt_kernel(int* __restrict__ cnt, int N) {
    int i = blockIdx.x * 256 + threadIdx.x;
    if (i < N) cnt[i] = 0;
}

__global__ void count_kernel(const int* __restrict__ dst, int* __restrict__ cnt, int E) {
    int i = blockIdx.x * blockDim.x + threadIdx.x;
    if (i < E) atomicAdd(&cnt[dst[i]], 1);
}

__global__ void block_sum_kernel(const int* __restrict__ cnt, int* __restrict__ bsum, int N) {
    __shared__ int sdata[256];
    int i = blockIdx.x * 256 + threadIdx.x;
    sdata[threadIdx.x] = (i < N) ? cnt[i] : 0;
    __syncthreads();
    for (int off = 128; off; off >>= 1) {
        if (threadIdx.x < off) sdata[threadIdx.x] += sdata[threadIdx.x + off];
        __syncthreads();
    }
    if (threadIdx.x == 0) bsum[blockIdx.x] = sdata[0];
}

__global__ void scan_bsum_kernel(int* bsum, int nb) {
    __shared__ int sdata[1024];
    int t = threadIdx.x;
    int v = (t < nb) ? bsum[t] : 0;
    sdata[t] = v;
    __syncthreads();
    for (int off = 1; off < 1024; off <<= 1) {
        int u = (t >= off) ? sdata[t - off] : 0;
        __syncthreads();
        sdata[t] += u;
        __syncthreads();
    }
    if (t < nb) bsum[t] = sdata[t] - v;   // exclusive
}

__global__ void scan_final_kernel(const int* __restrict__ cnt, const int* __restrict__ bsum,
                                  int* __restrict__ rowstart, int* __restrict__ fillpos,
                                  int N, int E) {
    __shared__ int sdata[256];
    int t = threadIdx.x;
    int i = blockIdx.x * 256 + t;
    int v = (i < N) ? cnt[i] : 0;
    sdata[t] = v;
    __syncthreads();
    for (int off = 1; off < 256; off <<= 1) {
        int u = (t >= off) ? sdata[t - off] : 0;
        __syncthreads();
        sdata[t] += u;
        __syncthreads();
    }
    if (i < N) {
        int r = bsum[blockIdx.x] + sdata[t] - v;
        rowstart[i] = r;
        fillpos[i]  = r;
    }
    if (i == 0) rowstart[N] = E;
}

__global__ void fill_kernel(const int* __restrict__ src, const int* __restrict__ dst,
                            int* __restrict__ fillpos, int* __restrict__ col, int E) {
    int i = blockIdx.x * blockDim.x + threadIdx.x;
    if (i < E) {
        int p = atomicAdd(&fillpos[dst[i]], 1);
        col[p] = src[i];
    }
}

// ---------------- casts / weight packs ----------------

__global__ void cast_x_kernel(const float* __restrict__ x, ushort* __restrict__ xb, int n4) {
    int i = blockIdx.x * 256 + threadIdx.x;
    if (i < n4) {
        float4 v = *reinterpret_cast<const float4*>(x + (size_t)i * 4);
        ushort4 o;
        o.x = f2bf(v.x); o.y = f2bf(v.y); o.z = f2bf(v.z); o.w = f2bf(v.w);
        *reinterpret_cast<ushort4*>(xb + (size_t)i * 4) = o;
    }
}

// Wb1[256][256] = [W1_l | W1_r]; Wb2[80][256] = [W2_l ; W2_r] (row-blocked)
__global__ void pack_w_kernel(const float* __restrict__ W1l, const float* __restrict__ W1r,
                              const float* __restrict__ W2l, const float* __restrict__ W2r,
                              ushort* __restrict__ Wb1, ushort* __restrict__ Wb2) {
    int i = blockIdx.x * 256 + threadIdx.x;
    if (i < 65536) {
        int n = i >> 8, k = i & 255;
        float v = (k < 128) ? W1l[n * 128 + k] : W1r[n * 128 + (k - 128)];
        Wb1[i] = f2bf(v);
    } else if (i < 65536 + 20480) {
        int j = i - 65536;
        int n = j >> 8, k = j & 255;
        float v = (n < 40) ? W2l[n * 256 + k] : W2r[(n - 40) * 256 + k];
        Wb2[j] = f2bf(v);
    }
}

// ---------------- mean aggregation layer 1 ----------------
// 4 edges in flight per wave: 4 groups x 16 lanes x 16B

__global__ __launch_bounds__(256) void agg128_kernel(const ushort* __restrict__ xb,
                                                     const int* __restrict__ rowstart,
                                                     const int* __restrict__ col,
                                                     ushort* __restrict__ aggb) {
    int wid = threadIdx.x >> 6, l = threadIdx.x & 63;
    int n = blockIdx.x * 4 + wid;
    if (n >= N_NODES) return;
    int g = l >> 4, lr = l & 15;
    int s = rowstart[n], e = rowstart[n + 1];
    float a[8] = {};
    for (int j = s + g; j < e; j += 4) {
        int c = col[j];
        uint4 v = *reinterpret_cast<const uint4*>(xb + (size_t)c * F_IN + lr * 8);
        a[0] += bf2f(v.x & 0xffffu); a[1] += bf2f(v.x >> 16);
        a[2] += bf2f(v.y & 0xffffu); a[3] += bf2f(v.y >> 16);
        a[4] += bf2f(v.z & 0xffffu); a[5] += bf2f(v.z >> 16);
        a[6] += bf2f(v.w & 0xffffu); a[7] += bf2f(v.w >> 16);
    }
#pragma unroll
    for (int i = 0; i < 8; ++i) {
        a[i] += __shfl_xor(a[i], 16);
        a[i] += __shfl_xor(a[i], 32);
    }
    if (g == 0) {
        float inv = 1.0f / (float)max(e - s, 1);
        uint4 o;
        o.x = (uint)f2bf(a[0] * inv) | ((uint)f2bf(a[1] * inv) << 16);
        o.y = (uint)f2bf(a[2] * inv) | ((uint)f2bf(a[3] * inv) << 16);
        o.z = (uint)f2bf(a[4] * inv) | ((uint)f2bf(a[5] * inv) << 16);
        o.w = (uint)f2bf(a[6] * inv) | ((uint)f2bf(a[7] * inv) << 16);
        *reinterpret_cast<uint4*>(aggb + (size_t)n * F_IN + lr * 8) = o;
    }
}

// ---------------- GEMM1: hb = relu([aggb|xb] @ Wb1.T + b1), bf16 out ----------------

__global__ __launch_bounds__(256) void gemm1_kernel(const ushort* __restrict__ aggb,
                                                    const ushort* __restrict__ xb,
                                                    const ushort* __restrict__ Wb1,
                                                    const float* __restrict__ b1,
                                                    ushort* __restrict__ hb) {
    __shared__ __align__(16) char Bls[128 * 512];   // 64 KiB
    const int t = threadIdx.x, w = t >> 6, l = t & 63;
    const int bm = blockIdx.x * 128, bn = blockIdx.y * 128;

    for (int i = t; i < 128 * 32; i += 256) {
        int n = i >> 5, k8 = (i & 31) * 8;
        uint4 v = *reinterpret_cast<const uint4*>(Wb1 + (size_t)(bn + n) * 256 + k8);
        *reinterpret_cast<uint4*>(Bls + ((n * 512 + k8 * 2) ^ ((n & 7) << 4))) = v;
    }
    __syncthreads();

    const int lr = l & 15, lg = l >> 4;
    f32x4 acc[2][8] = {};
#pragma unroll
    for (int kt = 0; kt < 8; ++kt) {
        const ushort* Ap = (kt < 4) ? aggb : xb;
        int kb = kt * 32 - ((kt < 4) ? 0 : 128) + lg * 8;
        bf16x8 a0 = *reinterpret_cast<const bf16x8*>(Ap + (size_t)(bm + w * 32 + lr) * F_IN + kb);
        bf16x8 a1 = *reinterpret_cast<const bf16x8*>(Ap + (size_t)(bm + w * 32 + 16 + lr) * F_IN + kb);
        int kbyte = kt * 64 + lg * 16;
#pragma unroll
        for (int j = 0; j < 8; ++j) {
            int nl = j * 16 + lr;
            bf16x8 b = *reinterpret_cast<const bf16x8*>(Bls + ((nl * 512 + kbyte) ^ ((nl & 7) << 4)));
            acc[0][j] = __builtin_amdgcn_mfma_f32_16x16x32_bf16(a0, b, acc[0][j], 0, 0, 0);
            acc[1][j] = __builtin_amdgcn_mfma_f32_16x16x32_bf16(a1, b, acc[1][j], 0, 0, 0);
        }
    }
#pragma unroll
    for (int m = 0; m < 2; ++m) {
        int rbase = bm + w * 32 + m * 16 + lg * 4;
#pragma unroll
        for (int j = 0; j < 8; ++j) {
            int c = bn + j * 16 + lr;
            float bias = b1[c];
#pragma unroll
            for (int r = 0; r < 4; ++r) {
                float v = acc[m][j][r] + bias;
                hb[(size_t)(rbase + r) * HID + c] = f2bf(fmaxf(v, 0.f));
            }
        }
    }
}

// ---------------- GEMM2: [hW | out_r] = hb @ Wb2.T ----------------
// cols 0-39 -> hWb bf16 (stride WPAD, cols 40-63 zeroed); cols 40-79 -> d_out fp32 (+b2)

__global__ __launch_bounds__(256) void gemm2_kernel(const ushort* __restrict__ hb,
                                                    const ushort* __restrict__ Wb2,
                                                    const float* __restrict__ b2,
                                                    ushort* __restrict__ hWb,
                                                    float* __restrict__ outp) {
    __shared__ __align__(16) char Bls[80 * 512];   // 40 KiB
    const int t = threadIdx.x, w = t >> 6, l = t & 63;
    const int bm = blockIdx.x * 128;

    for (int i = t; i < 80 * 32; i += 256) {
        int n = i >> 5, k8 = (i & 31) * 8;
        uint4 v = *reinterpret_cast<const uint4*>(Wb2 + (size_t)n * 256 + k8);
        *reinterpret_cast<uint4*>(Bls + ((n * 512 + k8 * 2) ^ ((n & 7) << 4))) = v;
    }
    __syncthreads();

    const int lr = l & 15, lg = l >> 4;
    f32x4 acc[2][5] = {};
#pragma unroll
    for (int kt = 0; kt < 8; ++kt) {
        int kb = kt * 32 + lg * 8;
        bf16x8 a0 = *reinterpret_cast<const bf16x8*>(hb + (size_t)(bm + w * 32 + lr) * HID + kb);
        bf16x8 a1 = *reinterpret_cast<const bf16x8*>(hb + (size_t)(bm + w * 32 + 16 + lr) * HID + kb);
        int kbyte = kt * 64 + lg * 16;
#pragma unroll
        for (int j = 0; j < 5; ++j) {
            int nl = j * 16 + lr;
            bf16x8 b = *reinterpret_cast<const bf16x8*>(Bls + ((nl * 512 + kbyte) ^ ((nl & 7) << 4)));
            acc[0][j] = __builtin_amdgcn_mfma_f32_16x16x32_bf16(a0, b, acc[0][j], 0, 0, 0);
            acc[1][j] = __builtin_amdgcn_mfma_f32_16x16x32_bf16(a1, b, acc[1][j], 0, 0, 0);
        }
    }
#pragma unroll
    for (int m = 0; m < 2; ++m) {
        int rbase = bm + w * 32 + m * 16 + lg * 4;
#pragma unroll
        for (int j = 0; j < 5; ++j) {
            int cfull = j * 16 + lr;
#pragma unroll
            for (int r = 0; r < 4; ++r) {
                int row = rbase + r;
                float v = acc[m][j][r];
                if (cfull < 40) {
                    hWb[(size_t)row * WPAD + cfull] = f2bf(v);
                } else {
                    if (cfull < 64) hWb[(size_t)row * WPAD + cfull] = 0;  // zero pad cols
                    if (row < N_NODES) {
                        int c = cfull - 40;
                        outp[(size_t)row * NCLS + c] = v + b2[c];
                    }
                }
            }
        }
    }
}

// ---------------- fused: out = log_softmax(out_partial + mean_j hW_j) ----------------
// 8 edges in flight per wave: 8 groups x 8 lanes x 16B (WPAD=64 bf16 rows)

__global__ __launch_bounds__(256) void agg40_lsm_kernel(const ushort* __restrict__ hWb,
                                                        const int* __restrict__ rowstart,
                                                        const int* __restrict__ col,
                                                        float* __restrict__ out) {
    int wid = threadIdx.x >> 6, l = threadIdx.x & 63;
    int n = blockIdx.x * 4 + wid;
    if (n >= N_NODES) return;
    int g = l >> 3, lr = l & 7;
    int s = rowstart[n], e = rowstart[n + 1];
    float a[8] = {};
    for (int j = s + g; j < e; j += 8) {
        int c = col[j];
        uint4 v = *reinterpret_cast<const uint4*>(hWb + (size_t)c * WPAD + lr * 8);
        a[0] += bf2f(v.x & 0xffffu); a[1] += bf2f(v.x >> 16);
        a[2] += bf2f(v.y & 0xffffu); a[3] += bf2f(v.y >> 16);
        a[4] += bf2f(v.z & 0xffffu); a[5] += bf2f(v.z >> 16);
        a[6] += bf2f(v.w & 0xffffu); a[7] += bf2f(v.w >> 16);
    }
#pragma unroll
    for (int i = 0; i < 8; ++i) {
        a[i] += __shfl_xor(a[i], 8);
        a[i] += __shfl_xor(a[i], 16);
        a[i] += __shfl_xor(a[i], 32);
    }
    // lanes 0-7 (g==0) hold class sums for classes lr*8..lr*8+7; lr<5 valid
    float inv = 1.0f / (float)max(e - s, 1);
    bool act = (g == 0) && (lr < 5);
    float v[8];
    if (act) {
        const float* pb = out + (size_t)n * NCLS + lr * 8;
        float4 p0 = *reinterpret_cast<const float4*>(pb);
        float4 p1 = *reinterpret_cast<const float4*>(pb + 4);
        v[0] = p0.x + a[0] * inv; v[1] = p0.y + a[1] * inv;
        v[2] = p0.z + a[2] * inv; v[3] = p0.w + a[3] * inv;
        v[4] = p1.x + a[4] * inv; v[5] = p1.y + a[5] * inv;
        v[6] = p1.z + a[6] * inv; v[7] = p1.w + a[7] * inv;
    } else {
#pragma unroll
        for (int i = 0; i < 8; ++i) v[i] = -INFINITY;
    }
    float m = v[0];
#pragma unroll
    for (int i = 1; i < 8; ++i) m = fmaxf(m, v[i]);
    m = fmaxf(m, __shfl_xor(m, 1));
    m = fmaxf(m, __shfl_xor(m, 2));
    m = fmaxf(m, __shfl_xor(m, 4));
    float ex = 0.f;
    if (act) {
#pragma unroll
        for (int i = 0; i < 8; ++i) ex += expf(v[i] - m);
    }
    ex += __shfl_xor(ex, 1);
    ex += __shfl_xor(ex, 2);
    ex += __shfl_xor(ex, 4);
    float ls = logf(ex);
    if (act) {
        float* ob = out + (size_t)n * NCLS + lr * 8;
        float4 o0, o1;
        o0.x = v[0] - m - ls; o0.y = v[1] - m - ls; o0.z = v[2] - m - ls; o0.w = v[3] - m - ls;
        o1.x = v[4] - m - ls; o1.y = v[5] - m - ls; o1.z = v[6] - m - ls; o1.w = v[7] - m - ls;
        *reinterpret_cast<float4*>(ob) = o0;
        *reinterpret_cast<float4*>(ob + 4) = o1;
    }
}

// ---------------- launch ----------------

static inline size_t align256(size_t x) { return (x + 255) & ~(size_t)255; }

extern "C" void kernel_launch(void* const* d_in, const int* in_sizes, int n_in,
                              void* d_out, int out_size, void* d_ws, size_t ws_size,
                              hipStream_t stream) {
    const float* x    = (const float*)d_in[0];
    const int*   ei   = (const int*)d_in[1];
    const float* W1l  = (const float*)d_in[2];
    const float* b1   = (const float*)d_in[3];
    const float* W1r  = (const float*)d_in[4];
    const float* W2l  = (const float*)d_in[5];
    const float* b2   = (const float*)d_in[6];
    const float* W2r  = (const float*)d_in[7];
    float* out = (float*)d_out;

    const int N = N_NODES;
    const int E = in_sizes[1] / 2;
    const int* srcArr = ei;
    const int* dstArr = ei + E;

    char* ws = (char*)d_ws;
    size_t off = 0;
    auto alloc = [&](size_t bytes) { size_t o = off; off = align256(off + bytes); return o; };
    int*    cnt      = (int*)(ws + alloc((size_t)N * 4));
    int*    rowstart = (int*)(ws + alloc((size_t)(N + 1) * 4));
    int*    fillpos  = (int*)(ws + alloc((size_t)N * 4));
    int*    col      = (int*)(ws + alloc((size_t)E * 4));
    int*    bsum     = (int*)(ws + alloc(1024 * 4));
    ushort* xb       = (ushort*)(ws + alloc((size_t)NPAD * F_IN * 2));
    ushort* aggb     = (ushort*)(ws + alloc((size_t)NPAD * F_IN * 2));
    ushort* hb       = (ushort*)(ws + alloc((size_t)NPAD * HID * 2));
    ushort* hWb      = (ushort*)(ws + alloc((size_t)NPAD * WPAD * 2));
    ushort* Wb1      = (ushort*)(ws + alloc((size_t)256 * 256 * 2));
    ushort* Wb2      = (ushort*)(ws + alloc((size_t)80 * 256 * 2));
    (void)ws_size; (void)n_in; (void)out_size;

    const int nbE = (E + 255) / 256;
    const int nbN = (N + 255) / 256;

    // CSR build (no runtime memsets — zero_cnt is our own kernel; pad rows of
    // xb/aggb/hb/hWb are never read on a path that reaches d_out)
    zero_cnt_kernel<<<nbN, 256, 0, stream>>>(cnt, N);
    count_kernel<<<nbE, 256, 0, stream>>>(dstArr, cnt, E);
    block_sum_kernel<<<nbN, 256, 0, stream>>>(cnt, bsum, N);
    scan_bsum_kernel<<<1, 1024, 0, stream>>>(bsum, nbN);
    scan_final_kernel<<<nbN, 256, 0, stream>>>(cnt, bsum, rowstart, fillpos, N, E);
    fill_kernel<<<nbE, 256, 0, stream>>>(srcArr, dstArr, fillpos, col, E);

    // casts / packs
    cast_x_kernel<<<(N * F_IN / 4 + 255) / 256, 256, 0, stream>>>(x, xb, N * F_IN / 4);
    pack_w_kernel<<<(65536 + 20480 + 255) / 256, 256, 0, stream>>>(W1l, W1r, W2l, W2r, Wb1, Wb2);

    // layer 1
    agg128_kernel<<<(N + 3) / 4, 256, 0, stream>>>(xb, rowstart, col, aggb);
    gemm1_kernel<<<dim3(NPAD / 128, 2), 256, 0, stream>>>(aggb, xb, Wb1, b1, hb);

    // layer 2 (transform-then-aggregate)
    gemm2_kernel<<<NPAD / 128, 256, 0, stream>>>(hb, Wb2, b2, hWb, out);
    agg40_lsm_kernel<<<(N + 3) / 4, 256, 0, stream>>>(hWb, rowstart, col, out);
}